// Round 15
// baseline (104.598 us; speedup 1.0000x reference)
//
#include <hip/hip_runtime.h>
#include <stdint.h>

#define SEQ   2048
#define DEMB  1024
#define NH    16
#define HD    64
#define MROWS 4096   // BS*SEQ

typedef __bf16 bf16x8 __attribute__((ext_vector_type(8)));
typedef __bf16 bf16x4 __attribute__((ext_vector_type(4)));
typedef float  f32x4  __attribute__((ext_vector_type(4)));

#define MFMA(a, b, c) __builtin_amdgcn_mfma_f32_16x16x32_bf16((a), (b), (c), 0, 0, 0)

static __device__ __forceinline__ uint16_t f2bf(float f) {
  union { __bf16 b; uint16_t u; } c;
  c.b = (__bf16)f;
  return c.u;
}

static __device__ __forceinline__ ushort4 pack4(f32x4 f) {
  union { bf16x4 b; ushort4 u; } c;
  c.b[0] = (__bf16)f[0]; c.b[1] = (__bf16)f[1];
  c.b[2] = (__bf16)f[2]; c.b[3] = (__bf16)f[3];
  return c.u;
}

// pack 2 f32 -> u32 of 2 bf16 (lo = a)
static __device__ __forceinline__ uint32_t pk2(float a, float b) {
  union { __bf16 h[2]; uint32_t u; } c;
  c.h[0] = (__bf16)a; c.h[1] = (__bf16)b;
  return c.u;
}

static __device__ __forceinline__ bf16x8 ldb8(const uint16_t* p) {
  union { uint4 i; bf16x8 b; } u;
  u.i = *(const uint4*)p;
  return u.b;
}

static __device__ __forceinline__ void gld_lds16(const uint16_t* g, uint16_t* l) {
  __builtin_amdgcn_global_load_lds(
      (const __attribute__((address_space(1))) uint32_t*)(g),
      (__attribute__((address_space(3))) uint32_t*)(l),
      16, 0, 0);
}

// ---------------------------------------------------------------- fused converts
__global__ __launch_bounds__(256) void cvt_all(const float* __restrict__ x,
                                               const float* __restrict__ wq,
                                               const float* __restrict__ wk,
                                               const float* __restrict__ wv,
                                               const float* __restrict__ wo,
                                               uint16_t* __restrict__ xb,
                                               uint16_t* __restrict__ wqkv,
                                               uint16_t* __restrict__ wob) {
  const int bid = blockIdx.x;
  const float* src; uint16_t* dst; int off;
  if (bid < 4096)      { src = x;  dst = xb;                 off = bid; }
  else if (bid < 5120) { src = wq; dst = wqkv;               off = bid - 4096; }
  else if (bid < 6144) { src = wk; dst = wqkv + (1u << 20);  off = bid - 5120; }
  else if (bid < 7168) { src = wv; dst = wqkv + (2u << 20);  off = bid - 6144; }
  else                 { src = wo; dst = wob;                off = bid - 7168; }
  const int i = (off * 256 + threadIdx.x) * 4;
  float4 v = *(const float4*)(src + i);
  f32x4 f; f[0] = v.x; f[1] = v.y; f[2] = v.z; f[3] = v.w;
  *(ushort4*)(dst + i) = pack4(f);
}

// ---------------------------------------------------------------- QKV GEMM
// (R10 exact: 256x192, BK=64, 8 waves 2Mx4N wave 128x48, grid 16x16 = 1/CU,
// 112 KB double-buffered LDS, conflict-free XOR swizzle, V^T via LDS slab)
__global__ __launch_bounds__(512, 2) void gemm_qkv(const uint16_t* __restrict__ A,
                                                   const uint16_t* __restrict__ B,
                                                   uint16_t* __restrict__ Cq,
                                                   uint16_t* __restrict__ Ck,
                                                   uint16_t* __restrict__ Cvt) {
  constexpr int K = 1024;
  __shared__ uint16_t lds[57344];      // 112 KB

  const int bcol = blockIdx.x * 192;
  const int brow = blockIdx.y << 8;

  const int t  = threadIdx.x;
  const int l  = t & 63;
  const int li = l & 15, lg = l >> 4;
  const int w  = t >> 6;               // 0..7
  const int wm = w >> 2;               // row half: wm*128
  const int wn = w & 3;                // col quarter: wn*48

  const int srow = t >> 3;
  const int scol = ((t & 7) ^ (srow & 7)) << 3;
  const uint16_t* gA = A + (size_t)(brow + srow) * K + scol;
  const uint16_t* gB = B + (size_t)(bcol + srow) * K + scol;

  auto stage = [&](int buf, int k0) {
    uint16_t* as = lds + buf * 16384;
    uint16_t* bs = lds + 32768 + buf * 12288;
    gld_lds16(gA + k0,                    as + t * 8);
    gld_lds16(gA + (size_t)64 * K + k0,   as + 4096 + t * 8);
    gld_lds16(gA + (size_t)128 * K + k0,  as + 8192 + t * 8);
    gld_lds16(gA + (size_t)192 * K + k0,  as + 12288 + t * 8);
    gld_lds16(gB + k0,                    bs + t * 8);
    gld_lds16(gB + (size_t)64 * K + k0,   bs + 4096 + t * 8);
    gld_lds16(gB + (size_t)128 * K + k0,  bs + 8192 + t * 8);
  };

  const int sw = li & 7;
  auto ldA = [&](int buf, int kh, int fi) {
    const int row = wm * 128 + fi * 16 + li;
    return ldb8(&lds[buf * 16384 + (row << 6) + ((((kh << 2) + lg) ^ sw) << 3)]);
  };
  auto ldB = [&](int buf, int kh, int ni) {
    const int row = wn * 48 + ni * 16 + li;
    return ldb8(&lds[32768 + buf * 12288 + (row << 6) + ((((kh << 2) + lg) ^ sw) << 3)]);
  };

  f32x4 acc[8][3] = {};

  stage(0, 0);
  __syncthreads();
  int cur = 0;

  for (int k0 = 0; k0 < K; k0 += 64) {
    if (k0 + 64 < K) stage(cur ^ 1, k0 + 64);

#pragma unroll
    for (int kh = 0; kh < 2; ++kh) {
      bf16x8 af[8], bfr[3];
#pragma unroll
      for (int ni = 0; ni < 3; ++ni) bfr[ni] = ldB(cur, kh, ni);
#pragma unroll
      for (int fi = 0; fi < 8; ++fi) af[fi] = ldA(cur, kh, fi);
      __builtin_amdgcn_s_setprio(1);
#pragma unroll
      for (int fi = 0; fi < 8; ++fi)
#pragma unroll
        for (int ni = 0; ni < 3; ++ni)
          acc[fi][ni] = MFMA(af[fi], bfr[ni], acc[fi][ni]);
      __builtin_amdgcn_s_setprio(0);
    }

    __syncthreads();
    cur ^= 1;
  }

  // ---- epilogue. Q/K: direct stores. V: per-wave LDS transpose -> coalesced.
  uint16_t* slab = lds + w * 6800;
  bool anyV = false;

#pragma unroll
  for (int mi = 0; mi < 8; ++mi) {
#pragma unroll
    for (int ni = 0; ni < 3; ++ni) {
      const int col = bcol + wn * 48 + ni * 16 + li;
      const int row = brow + wm * 128 + mi * 16 + lg * 4;   // + r
      if (col < 1024) {
#pragma unroll
        for (int r = 0; r < 4; ++r)
          Cq[(size_t)(row + r) * 1024 + col] = f2bf(acc[mi][ni][r] * 0.18033688f);
      } else if (col < 2048) {
#pragma unroll
        for (int r = 0; r < 4; ++r)
          Ck[(size_t)(row + r) * 1024 + (col - 1024)] = f2bf(acc[mi][ni][r]);
      } else {
        anyV = true;
        *(ushort4*)&slab[(ni * 16 + li) * 136 + mi * 16 + lg * 4] = pack4(acc[mi][ni]);
      }
    }
  }

  if (anyV) {
    asm volatile("s_waitcnt lgkmcnt(0)" ::: "memory");
    const int m0 = brow + wm * 128;
    const size_t mbase = (size_t)((m0 >> 11) << 10) * 2048 + (m0 & 2047);
#pragma unroll
    for (int cc = 0; cc < 12; ++cc) {
      const int c_loc = cc * 4 + lg;
      const int cglob = bcol + wn * 48 + c_loc;
      if (cglob >= 2048) {
        const int c = cglob - 2048;
        uint4 v = *(const uint4*)&slab[c_loc * 136 + li * 8];
        *(uint4*)(Cvt + (size_t)c * 2048 + mbase + li * 8) = v;
      }
    }
  }
}

// ---------------------------------------------------------------- out projection
// (R10 exact: 128x128, BK=64, 8 waves wave 64x32, grid 8x32 = 1/CU)
__global__ __launch_bounds__(512, 2) void gemm_out(const uint16_t* __restrict__ A,
                                                   const uint16_t* __restrict__ B,
                                                   float* __restrict__ Cf,
                                                   const float* __restrict__ bias) {
  constexpr int K = 1024;
  __shared__ uint16_t As[2][128 * 64];
  __shared__ uint16_t Bs[2][128 * 64];

  const int bcol = blockIdx.x << 7;
  const int brow = blockIdx.y << 7;

  const int t  = threadIdx.x;
  const int l  = t & 63;
  const int li = l & 15, lg = l >> 4;
  const int w  = t >> 6;
  const int wm = w >> 2;
  const int wn = w & 3;

  const int srow = t >> 3;
  const int scol = ((t & 7) ^ (srow & 7)) << 3;
  const uint16_t* gA = A + (size_t)(brow + srow) * K + scol;
  const uint16_t* gB = B + (size_t)(bcol + srow) * K + scol;

  auto stage = [&](int buf, int k0) {
    gld_lds16(gA + k0,                  &As[buf][t * 8]);
    gld_lds16(gA + (size_t)64 * K + k0, &As[buf][4096 + t * 8]);
    gld_lds16(gB + k0,                  &Bs[buf][t * 8]);
    gld_lds16(gB + (size_t)64 * K + k0, &Bs[buf][4096 + t * 8]);
  };

  const int sw = li & 7;
  auto ldA = [&](int buf, int kh, int fi) {
    const int row = wm * 64 + fi * 16 + li;
    return ldb8(&As[buf][(row << 6) + ((((kh << 2) + lg) ^ sw) << 3)]);
  };
  auto ldB = [&](int buf, int kh, int ni) {
    const int row = wn * 32 + ni * 16 + li;
    return ldb8(&Bs[buf][(row << 6) + ((((kh << 2) + lg) ^ sw) << 3)]);
  };

  f32x4 acc[4][2] = {};

  stage(0, 0);
  __syncthreads();
  int cur = 0;

  for (int k0 = 0; k0 < K; k0 += 64) {
    if (k0 + 64 < K) stage(cur ^ 1, k0 + 64);

#pragma unroll
    for (int kh = 0; kh < 2; ++kh) {
      bf16x8 af[4], bfr[2];
#pragma unroll
      for (int ni = 0; ni < 2; ++ni) bfr[ni] = ldB(cur, kh, ni);
#pragma unroll
      for (int fi = 0; fi < 4; ++fi) af[fi] = ldA(cur, kh, fi);
      __builtin_amdgcn_s_setprio(1);
#pragma unroll
      for (int fi = 0; fi < 4; ++fi)
#pragma unroll
        for (int ni = 0; ni < 2; ++ni)
          acc[fi][ni] = MFMA(af[fi], bfr[ni], acc[fi][ni]);
      __builtin_amdgcn_s_setprio(0);
    }

    __syncthreads();
    cur ^= 1;
  }

#pragma unroll
  for (int mi = 0; mi < 4; ++mi) {
#pragma unroll
    for (int ni = 0; ni < 2; ++ni) {
      const int row = brow + wm * 64 + mi * 16 + lg * 4;
      const int col = bcol + wn * 32 + ni * 16 + li;
      const float bv = bias[col];
#pragma unroll
      for (int r = 0; r < 4; ++r)
        Cf[(size_t)(row + r) * 1024 + col] = acc[mi][ni][r] + bv;
    }
  }
}

// ---------------------------------------------------------------- flash attention
// R10 structure (4-wave, QBLK=64, causal-paired 512 blocks, XCD head-grouped,
// double-buffered swizzled K/V, no-max exp2 softmax). R15: the P-LDS round
// trip (ds_write + lgkmcnt + ds_read_b128) is replaced by an IN-REGISTER
// exchange: P values packed to bf16 pairs, moved across the 4 lg-groups
// (same li) with 16 independent ds_bpermute_b32 + cndmask selects.
// Derivation: PV B-frag needs P[key=lg*8+j][q=li]; lane holds
// P[key=tt*16+lg*4+r][q=li] -> source tt=lg>>1 (pb0) / 2+(lg>>1) (pb1),
// source lanes lg' = 2*(lg&1), 2*(lg&1)+1, r=j&3. P slab removed (LDS 32KB).
__global__ __launch_bounds__(256, 2) void attn_fwd(const uint16_t* __restrict__ Q,
                                                   const uint16_t* __restrict__ K,
                                                   const uint16_t* __restrict__ Vt,
                                                   uint16_t* __restrict__ ctx) {
  const int id   = blockIdx.x;
  const int rank = id >> 3;                  // 0..63
  const int bh   = (id & 7) * 4 + (rank >> 4);
  const int pr   = rank & 15;                // pair index 0..15
  const int b = bh >> 4, h = bh & 15;

  const int t  = threadIdx.x;
  const int w  = t >> 6, l = t & 63;
  const int li = l & 15, lg = l >> 4;

  __shared__ uint16_t Kl[2][64 * 64];   // 8KB x2 (key, d), swizzled
  __shared__ uint16_t Vl[2][64 * 64];   // 8KB x2 (d, key), swizzled

  const uint16_t* Kg = K + (size_t)(b * 2048) * 1024 + h * 64;
  const uint16_t* Vg = Vt + (size_t)(b * 1024 + h * 64) * 2048;

  const int srow = t >> 3;                          // 0..31
  const int scol = ((t & 7) * 8) ^ ((srow & 7) * 8);

  auto stage = [&](int buf, int kt2) {
    const int kb2 = kt2 << 6;
    gld_lds16(Kg + (size_t)(kb2 + srow) * 1024 + scol,      &Kl[buf][t * 8]);
    gld_lds16(Kg + (size_t)(kb2 + 32 + srow) * 1024 + scol, &Kl[buf][2048 + t * 8]);
    gld_lds16(Vg + (size_t)srow * 2048 + kb2 + scol,        &Vl[buf][t * 8]);
    gld_lds16(Vg + (size_t)(32 + srow) * 2048 + kb2 + scol, &Vl[buf][2048 + t * 8]);
  };

  const int fsw = (li & 7) * 8;
  // bpermute byte indices: source lanes a*16+li and (a+1)*16+li, a=2*(lg&1)
  const int ia = (((lg & 1) << 5) + li) << 2;
  const int ib = ia + 64;
  const bool hi_tt = (lg >> 1) & 1;     // pb0 uses tt1 (else tt0); pb1: tt3/tt2
  int cur = 0;

#pragma unroll 1
  for (int ph = 0; ph < 2; ++ph) {
    const int qbl  = ph ? (31 - pr) : pr;
    const int qrow = (qbl << 6) + (w << 4);
    const uint16_t* qp = Q + (size_t)(b * 2048 + qrow + li) * 1024 + h * 64 + lg * 8;
    const bf16x8 q0 = ldb8(qp);
    const bf16x8 q1 = ldb8(qp + 32);

    f32x4 o[4] = {};                   // O[d = dt*16 + lg*4 + r][q = li]
    float l_r = 0.f;

    stage(cur, 0);
    __syncthreads();

    for (int kt = 0; kt <= qbl; ++kt) {
      if (kt < qbl) stage(cur ^ 1, kt + 1);

      const uint16_t* Kc = &Kl[cur][0];
      const uint16_t* Vc = &Vl[cur][0];

      // QK^T swapped: s[tt][r] = S[key = kt*64+tt*16+lg*4+r][q = qrow+li]
      f32x4 s[4];
      __builtin_amdgcn_s_setprio(1);
#pragma unroll
      for (int tt = 0; tt < 4; ++tt) {
        const uint16_t* kr = Kc + (tt * 16 + li) * 64;
        f32x4 z = {};
        z = MFMA(ldb8(kr + ((lg * 8) ^ fsw)), q0, z);
        z = MFMA(ldb8(kr + ((32 + lg * 8) ^ fsw)), q1, z);
        s[tt] = z;
      }
      __builtin_amdgcn_s_setprio(0);

      // V fragments: lane holds V[d = dt*16 + li][key = half*32 + lg*8 + j]
      bf16x8 vf[4][2];
#pragma unroll
      for (int dt = 0; dt < 4; ++dt) {
        const uint16_t* vr = Vc + (dt * 16 + li) * 64;
        vf[dt][0] = ldb8(vr + ((lg * 8) ^ fsw));
        vf[dt][1] = ldb8(vr + ((32 + lg * 8) ^ fsw));
      }

      if (kt == qbl) {   // diagonal tile: causal mask -> exp2 gives exact 0
        const int qloc = (w << 4) + li;
#pragma unroll
        for (int tt = 0; tt < 4; ++tt) {
          const int key = (tt << 4) + (lg << 2);
#pragma unroll
          for (int r = 0; r < 4; ++r)
            if (key + r > qloc) s[tt][r] = -1e30f;
        }
      }

      // ---- no-max softmax: P = exp2(s); pack pairs to bf16 words
      uint32_t w0[4], w1[4];
      float lsum = 0.f;
#pragma unroll
      for (int tt = 0; tt < 4; ++tt) {
        const float p0 = __builtin_amdgcn_exp2f(s[tt][0]);
        const float p1 = __builtin_amdgcn_exp2f(s[tt][1]);
        const float p2 = __builtin_amdgcn_exp2f(s[tt][2]);
        const float p3 = __builtin_amdgcn_exp2f(s[tt][3]);
        lsum += (p0 + p1) + (p2 + p3);
        w0[tt] = pk2(p0, p1);
        w1[tt] = pk2(p2, p3);
      }
      l_r += lsum;

      // ---- in-register P redistribution (replaces P-LDS round trip)
      // pb0 = keys lg*8+0..7 (tile half 0): words
      //  [w0(src a, tt), w1(a, tt), w0(a+1, tt), w1(a+1, tt)], tt = lg>>1
      uint4 pbw0, pbw1;
      {
        const uint32_t a0 = __builtin_amdgcn_ds_bpermute(ia, w0[0]);
        const uint32_t a1 = __builtin_amdgcn_ds_bpermute(ia, w0[1]);
        const uint32_t b0 = __builtin_amdgcn_ds_bpermute(ia, w1[0]);
        const uint32_t b1 = __builtin_amdgcn_ds_bpermute(ia, w1[1]);
        const uint32_t c0 = __builtin_amdgcn_ds_bpermute(ib, w0[0]);
        const uint32_t c1 = __builtin_amdgcn_ds_bpermute(ib, w0[1]);
        const uint32_t d0 = __builtin_amdgcn_ds_bpermute(ib, w1[0]);
        const uint32_t d1 = __builtin_amdgcn_ds_bpermute(ib, w1[1]);
        pbw0.x = hi_tt ? a1 : a0;
        pbw0.y = hi_tt ? b1 : b0;
        pbw0.z = hi_tt ? c1 : c0;
        pbw0.w = hi_tt ? d1 : d0;
      }
      {
        const uint32_t a0 = __builtin_amdgcn_ds_bpermute(ia, w0[2]);
        const uint32_t a1 = __builtin_amdgcn_ds_bpermute(ia, w0[3]);
        const uint32_t b0 = __builtin_amdgcn_ds_bpermute(ia, w1[2]);
        const uint32_t b1 = __builtin_amdgcn_ds_bpermute(ia, w1[3]);
        const uint32_t c0 = __builtin_amdgcn_ds_bpermute(ib, w0[2]);
        const uint32_t c1 = __builtin_amdgcn_ds_bpermute(ib, w0[3]);
        const uint32_t d0 = __builtin_amdgcn_ds_bpermute(ib, w1[2]);
        const uint32_t d1 = __builtin_amdgcn_ds_bpermute(ib, w1[3]);
        pbw1.x = hi_tt ? a1 : a0;
        pbw1.y = hi_tt ? b1 : b0;
        pbw1.z = hi_tt ? c1 : c0;
        pbw1.w = hi_tt ? d1 : d0;
      }
      union { uint4 i; bf16x8 b; } u0, u1;
      u0.i = pbw0; u1.i = pbw1;
      const bf16x8 pb0 = u0.b;
      const bf16x8 pb1 = u1.b;

      __builtin_amdgcn_s_setprio(1);
#pragma unroll
      for (int dt = 0; dt < 4; ++dt) {
        o[dt] = MFMA(vf[dt][0], pb0, o[dt]);
        o[dt] = MFMA(vf[dt][1], pb1, o[dt]);
      }
      __builtin_amdgcn_s_setprio(0);

      __syncthreads();
      cur ^= 1;
    }

    // final l reduce across the 4 lg-groups sharing q = li
    l_r += __shfl_xor(l_r, 16);
    l_r += __shfl_xor(l_r, 32);
    const float inv = 1.0f / l_r;
    const int qg = b * 2048 + qrow + li;
#pragma unroll
    for (int dt = 0; dt < 4; ++dt) {
      f32x4 ov = o[dt];
      ov[0] *= inv; ov[1] *= inv; ov[2] *= inv; ov[3] *= inv;
      *(ushort4*)(ctx + (size_t)qg * 1024 + h * 64 + (dt << 4) + (lg << 2)) = pack4(ov);
    }
  }
}

// ---------------------------------------------------------------- launch
extern "C" void kernel_launch(void* const* d_in, const int* in_sizes, int n_in,
                              void* d_out, int out_size, void* d_ws, size_t ws_size,
                              hipStream_t stream) {
  const float* x  = (const float*)d_in[0];
  const float* Wq = (const float*)d_in[1];
  const float* Wk = (const float*)d_in[2];
  const float* Wv = (const float*)d_in[3];
  const float* Wo = (const float*)d_in[4];
  const float* bo = (const float*)d_in[5];
  float* out = (float*)d_out;

  char* ws = (char*)d_ws;
  uint16_t* xb   = (uint16_t*)(ws);                 // 8MB (dead after QKV gemm)
  uint16_t* Wqkv = (uint16_t*)(ws + ( 8u << 20));   // 6MB: Wq|Wk|Wv contiguous
  uint16_t* Wob  = (uint16_t*)(ws + (14u << 20));   // 2MB
  uint16_t* Qb   = (uint16_t*)(ws + (16u << 20));   // 8MB
  uint16_t* Kb   = (uint16_t*)(ws + (24u << 20));   // 8MB
  uint16_t* Vt   = (uint16_t*)(ws + (32u << 20));   // 8MB
  uint16_t* Ctx  = (uint16_t*)(ws);                 // overlays xb

  cvt_all<<<8192, 256, 0, stream>>>(x, Wq, Wk, Wv, Wo, xb, Wqkv, Wob);

  // fused QKV projection: 256x192 tiles, grid 16x16 = 256 blocks (1/CU)
  gemm_qkv<<<dim3(16, 16), 512, 0, stream>>>(xb, Wqkv, Qb, Kb, Vt);

  // attention: 512 blocks (XCD-mapped, causal-paired), 4 waves, bpermute-P
  attn_fwd<<<512, 256, 0, stream>>>(Qb, Kb, Vt, Ctx);

  // output projection + bias: 128x128 tiles, grid 8x32 = 256 blocks (1/CU)
  gemm_out<<<dim3(8, 32), 512, 0, stream>>>(Ctx, Wob, out, bo);
}

// Round 16
// 101.417 us; speedup vs baseline: 1.0314x; 1.0314x over previous
//
#include <hip/hip_runtime.h>
#include <stdint.h>

#define SEQ   2048
#define DEMB  1024
#define NH    16
#define HD    64
#define MROWS 4096   // BS*SEQ

typedef __bf16 bf16x8 __attribute__((ext_vector_type(8)));
typedef __bf16 bf16x4 __attribute__((ext_vector_type(4)));
typedef float  f32x4  __attribute__((ext_vector_type(4)));

#define MFMA(a, b, c) __builtin_amdgcn_mfma_f32_16x16x32_bf16((a), (b), (c), 0, 0, 0)

static __device__ __forceinline__ uint16_t f2bf(float f) {
  union { __bf16 b; uint16_t u; } c;
  c.b = (__bf16)f;
  return c.u;
}

static __device__ __forceinline__ ushort4 pack4(f32x4 f) {
  union { bf16x4 b; ushort4 u; } c;
  c.b[0] = (__bf16)f[0]; c.b[1] = (__bf16)f[1];
  c.b[2] = (__bf16)f[2]; c.b[3] = (__bf16)f[3];
  return c.u;
}

static __device__ __forceinline__ bf16x8 ldb8(const uint16_t* p) {
  union { uint4 i; bf16x8 b; } u;
  u.i = *(const uint4*)p;
  return u.b;
}

static __device__ __forceinline__ void gld_lds16(const uint16_t* g, uint16_t* l) {
  __builtin_amdgcn_global_load_lds(
      (const __attribute__((address_space(1))) uint32_t*)(g),
      (__attribute__((address_space(3))) uint32_t*)(l),
      16, 0, 0);
}

// ---------------------------------------------------------------- fused converts
__global__ __launch_bounds__(256) void cvt_all(const float* __restrict__ x,
                                               const float* __restrict__ wq,
                                               const float* __restrict__ wk,
                                               const float* __restrict__ wv,
                                               const float* __restrict__ wo,
                                               uint16_t* __restrict__ xb,
                                               uint16_t* __restrict__ wqkv,
                                               uint16_t* __restrict__ wob) {
  const int bid = blockIdx.x;
  const float* src; uint16_t* dst; int off;
  if (bid < 4096)      { src = x;  dst = xb;                 off = bid; }
  else if (bid < 5120) { src = wq; dst = wqkv;               off = bid - 4096; }
  else if (bid < 6144) { src = wk; dst = wqkv + (1u << 20);  off = bid - 5120; }
  else if (bid < 7168) { src = wv; dst = wqkv + (2u << 20);  off = bid - 6144; }
  else                 { src = wo; dst = wob;                off = bid - 7168; }
  const int i = (off * 256 + threadIdx.x) * 4;
  float4 v = *(const float4*)(src + i);
  f32x4 f; f[0] = v.x; f[1] = v.y; f[2] = v.z; f[3] = v.w;
  *(ushort4*)(dst + i) = pack4(f);
}

// ---------------------------------------------------------------- QKV GEMM
// (R10 exact: 256x192, BK=64, 8 waves 2Mx4N wave 128x48, grid 16x16 = 1/CU,
// 112 KB double-buffered LDS, conflict-free XOR swizzle, V^T via LDS slab)
__global__ __launch_bounds__(512, 2) void gemm_qkv(const uint16_t* __restrict__ A,
                                                   const uint16_t* __restrict__ B,
                                                   uint16_t* __restrict__ Cq,
                                                   uint16_t* __restrict__ Ck,
                                                   uint16_t* __restrict__ Cvt) {
  constexpr int K = 1024;
  __shared__ uint16_t lds[57344];      // 112 KB

  const int bcol = blockIdx.x * 192;
  const int brow = blockIdx.y << 8;

  const int t  = threadIdx.x;
  const int l  = t & 63;
  const int li = l & 15, lg = l >> 4;
  const int w  = t >> 6;               // 0..7
  const int wm = w >> 2;               // row half: wm*128
  const int wn = w & 3;                // col quarter: wn*48

  const int srow = t >> 3;
  const int scol = ((t & 7) ^ (srow & 7)) << 3;
  const uint16_t* gA = A + (size_t)(brow + srow) * K + scol;
  const uint16_t* gB = B + (size_t)(bcol + srow) * K + scol;

  auto stage = [&](int buf, int k0) {
    uint16_t* as = lds + buf * 16384;
    uint16_t* bs = lds + 32768 + buf * 12288;
    gld_lds16(gA + k0,                    as + t * 8);
    gld_lds16(gA + (size_t)64 * K + k0,   as + 4096 + t * 8);
    gld_lds16(gA + (size_t)128 * K + k0,  as + 8192 + t * 8);
    gld_lds16(gA + (size_t)192 * K + k0,  as + 12288 + t * 8);
    gld_lds16(gB + k0,                    bs + t * 8);
    gld_lds16(gB + (size_t)64 * K + k0,   bs + 4096 + t * 8);
    gld_lds16(gB + (size_t)128 * K + k0,  bs + 8192 + t * 8);
  };

  const int sw = li & 7;
  auto ldA = [&](int buf, int kh, int fi) {
    const int row = wm * 128 + fi * 16 + li;
    return ldb8(&lds[buf * 16384 + (row << 6) + ((((kh << 2) + lg) ^ sw) << 3)]);
  };
  auto ldB = [&](int buf, int kh, int ni) {
    const int row = wn * 48 + ni * 16 + li;
    return ldb8(&lds[32768 + buf * 12288 + (row << 6) + ((((kh << 2) + lg) ^ sw) << 3)]);
  };

  f32x4 acc[8][3] = {};

  stage(0, 0);
  __syncthreads();
  int cur = 0;

  for (int k0 = 0; k0 < K; k0 += 64) {
    if (k0 + 64 < K) stage(cur ^ 1, k0 + 64);

#pragma unroll
    for (int kh = 0; kh < 2; ++kh) {
      bf16x8 af[8], bfr[3];
#pragma unroll
      for (int ni = 0; ni < 3; ++ni) bfr[ni] = ldB(cur, kh, ni);
#pragma unroll
      for (int fi = 0; fi < 8; ++fi) af[fi] = ldA(cur, kh, fi);
      __builtin_amdgcn_s_setprio(1);
#pragma unroll
      for (int fi = 0; fi < 8; ++fi)
#pragma unroll
        for (int ni = 0; ni < 3; ++ni)
          acc[fi][ni] = MFMA(af[fi], bfr[ni], acc[fi][ni]);
      __builtin_amdgcn_s_setprio(0);
    }

    __syncthreads();
    cur ^= 1;
  }

  // ---- epilogue. Q/K: direct stores. V: per-wave LDS transpose -> coalesced.
  uint16_t* slab = lds + w * 6800;
  bool anyV = false;

#pragma unroll
  for (int mi = 0; mi < 8; ++mi) {
#pragma unroll
    for (int ni = 0; ni < 3; ++ni) {
      const int col = bcol + wn * 48 + ni * 16 + li;
      const int row = brow + wm * 128 + mi * 16 + lg * 4;   // + r
      if (col < 1024) {
#pragma unroll
        for (int r = 0; r < 4; ++r)
          Cq[(size_t)(row + r) * 1024 + col] = f2bf(acc[mi][ni][r] * 0.18033688f);
      } else if (col < 2048) {
#pragma unroll
        for (int r = 0; r < 4; ++r)
          Ck[(size_t)(row + r) * 1024 + (col - 1024)] = f2bf(acc[mi][ni][r]);
      } else {
        anyV = true;
        *(ushort4*)&slab[(ni * 16 + li) * 136 + mi * 16 + lg * 4] = pack4(acc[mi][ni]);
      }
    }
  }

  if (anyV) {
    asm volatile("s_waitcnt lgkmcnt(0)" ::: "memory");
    const int m0 = brow + wm * 128;
    const size_t mbase = (size_t)((m0 >> 11) << 10) * 2048 + (m0 & 2047);
#pragma unroll
    for (int cc = 0; cc < 12; ++cc) {
      const int c_loc = cc * 4 + lg;
      const int cglob = bcol + wn * 48 + c_loc;
      if (cglob >= 2048) {
        const int c = cglob - 2048;
        uint4 v = *(const uint4*)&slab[c_loc * 136 + li * 8];
        *(uint4*)(Cvt + (size_t)c * 2048 + mbase + li * 8) = v;
      }
    }
  }
}

// ---------------------------------------------------------------- out projection
// (R10 exact: 128x128, BK=64, 8 waves wave 64x32, grid 8x32 = 1/CU)
__global__ __launch_bounds__(512, 2) void gemm_out(const uint16_t* __restrict__ A,
                                                   const uint16_t* __restrict__ B,
                                                   float* __restrict__ Cf,
                                                   const float* __restrict__ bias) {
  constexpr int K = 1024;
  __shared__ uint16_t As[2][128 * 64];
  __shared__ uint16_t Bs[2][128 * 64];

  const int bcol = blockIdx.x << 7;
  const int brow = blockIdx.y << 7;

  const int t  = threadIdx.x;
  const int l  = t & 63;
  const int li = l & 15, lg = l >> 4;
  const int w  = t >> 6;
  const int wm = w >> 2;
  const int wn = w & 3;

  const int srow = t >> 3;
  const int scol = ((t & 7) ^ (srow & 7)) << 3;
  const uint16_t* gA = A + (size_t)(brow + srow) * K + scol;
  const uint16_t* gB = B + (size_t)(bcol + srow) * K + scol;

  auto stage = [&](int buf, int k0) {
    gld_lds16(gA + k0,                  &As[buf][t * 8]);
    gld_lds16(gA + (size_t)64 * K + k0, &As[buf][4096 + t * 8]);
    gld_lds16(gB + k0,                  &Bs[buf][t * 8]);
    gld_lds16(gB + (size_t)64 * K + k0, &Bs[buf][4096 + t * 8]);
  };

  const int sw = li & 7;
  auto ldA = [&](int buf, int kh, int fi) {
    const int row = wm * 64 + fi * 16 + li;
    return ldb8(&As[buf][(row << 6) + ((((kh << 2) + lg) ^ sw) << 3)]);
  };
  auto ldB = [&](int buf, int kh, int ni) {
    const int row = wn * 32 + ni * 16 + li;
    return ldb8(&Bs[buf][(row << 6) + ((((kh << 2) + lg) ^ sw) << 3)]);
  };

  f32x4 acc[4][2] = {};

  stage(0, 0);
  __syncthreads();
  int cur = 0;

  for (int k0 = 0; k0 < K; k0 += 64) {
    if (k0 + 64 < K) stage(cur ^ 1, k0 + 64);

#pragma unroll
    for (int kh = 0; kh < 2; ++kh) {
      bf16x8 af[4], bfr[2];
#pragma unroll
      for (int ni = 0; ni < 2; ++ni) bfr[ni] = ldB(cur, kh, ni);
#pragma unroll
      for (int fi = 0; fi < 4; ++fi) af[fi] = ldA(cur, kh, fi);
      __builtin_amdgcn_s_setprio(1);
#pragma unroll
      for (int fi = 0; fi < 4; ++fi)
#pragma unroll
        for (int ni = 0; ni < 2; ++ni)
          acc[fi][ni] = MFMA(af[fi], bfr[ni], acc[fi][ni]);
      __builtin_amdgcn_s_setprio(0);
    }

    __syncthreads();
    cur ^= 1;
  }

#pragma unroll
  for (int mi = 0; mi < 4; ++mi) {
#pragma unroll
    for (int ni = 0; ni < 2; ++ni) {
      const int row = brow + wm * 64 + mi * 16 + lg * 4;
      const int col = bcol + wn * 32 + ni * 16 + li;
      const float bv = bias[col];
#pragma unroll
      for (int r = 0; r < 4; ++r)
        Cf[(size_t)(row + r) * 1024 + col] = acc[mi][ni][r] + bv;
    }
  }
}

// ---------------------------------------------------------------- flash attention
// R10 inner body EXACT (4-wave, QBLK=64, double-buffered swizzled K/V, P-LDS
// slab, no-max exp2 softmax, setprio). R16: BALANCED 704-BLOCK partition for
// ~2.75 blocks/CU residency (vs R10's exact-2): per (b,h) the 32 q-blocks
// form 22 groups -- 12 singletons (qbl 20..31: 21-32 tiles) + 10 pairs
// (19-p, p): 21 tiles -- tile counts in [21,32], mean 24 (R14's 1024
// singletons spanned [1,32] and regressed). XCD head-grouping kept.
__global__ __launch_bounds__(256, 3) void attn_fwd(const uint16_t* __restrict__ Q,
                                                   const uint16_t* __restrict__ K,
                                                   const uint16_t* __restrict__ Vt,
                                                   uint16_t* __restrict__ ctx) {
  const int id   = blockIdx.x;               // 0..703; id&7 = XCD
  const int rank = id >> 3;                  // 0..87
  const int bh   = (id & 7) * 4 + rank / 22;
  const int g    = rank % 22;                // group within (b,h)
  const int b = bh >> 4, h = bh & 15;

  int q0, q1, nph;
  if (g < 12) { q0 = 31 - g; q1 = 0; nph = 1; }          // 21..32 tiles
  else        { int p = g - 12; q0 = 19 - p; q1 = p; nph = 2; }  // 21 tiles

  const int t  = threadIdx.x;
  const int w  = t >> 6, l = t & 63;
  const int li = l & 15, lg = l >> 4;

  __shared__ uint16_t Kl[2][64 * 64];   // 8KB x2 (key, d), swizzled
  __shared__ uint16_t Vl[2][64 * 64];   // 8KB x2 (d, key), swizzled
  __shared__ uint16_t P[4][16][72];     // per-wave P slab

  const uint16_t* Kg = K + (size_t)(b * 2048) * 1024 + h * 64;
  const uint16_t* Vg = Vt + (size_t)(b * 1024 + h * 64) * 2048;

  const int srow = t >> 3;                          // 0..31
  const int scol = ((t & 7) * 8) ^ ((srow & 7) * 8);

  auto stage = [&](int buf, int kt2) {
    const int kb2 = kt2 << 6;
    gld_lds16(Kg + (size_t)(kb2 + srow) * 1024 + scol,      &Kl[buf][t * 8]);
    gld_lds16(Kg + (size_t)(kb2 + 32 + srow) * 1024 + scol, &Kl[buf][2048 + t * 8]);
    gld_lds16(Vg + (size_t)srow * 2048 + kb2 + scol,        &Vl[buf][t * 8]);
    gld_lds16(Vg + (size_t)(32 + srow) * 2048 + kb2 + scol, &Vl[buf][2048 + t * 8]);
  };

  const int fsw = (li & 7) * 8;
  int cur = 0;

#pragma unroll 1
  for (int ph = 0; ph < nph; ++ph) {
    const int qbl  = ph ? q1 : q0;
    const int qrow = (qbl << 6) + (w << 4);
    const uint16_t* qp = Q + (size_t)(b * 2048 + qrow + li) * 1024 + h * 64 + lg * 8;
    const bf16x8 q0v = ldb8(qp);
    const bf16x8 q1v = ldb8(qp + 32);

    f32x4 o[4] = {};                   // O[d = dt*16 + lg*4 + r][q = li]
    float l_r = 0.f;

    stage(cur, 0);
    __syncthreads();

    for (int kt = 0; kt <= qbl; ++kt) {
      if (kt < qbl) stage(cur ^ 1, kt + 1);

      const uint16_t* Kc = &Kl[cur][0];
      const uint16_t* Vc = &Vl[cur][0];

      // QK^T swapped: s[tt][r] = S[key = kt*64+tt*16+lg*4+r][q = qrow+li]
      f32x4 s[4];
      __builtin_amdgcn_s_setprio(1);
#pragma unroll
      for (int tt = 0; tt < 4; ++tt) {
        const uint16_t* kr = Kc + (tt * 16 + li) * 64;
        f32x4 z = {};
        z = MFMA(ldb8(kr + ((lg * 8) ^ fsw)), q0v, z);
        z = MFMA(ldb8(kr + ((32 + lg * 8) ^ fsw)), q1v, z);
        s[tt] = z;
      }
      __builtin_amdgcn_s_setprio(0);

      // V fragments: lane holds V[d = dt*16 + li][key = half*32 + lg*8 + j]
      bf16x8 vf[4][2];
#pragma unroll
      for (int dt = 0; dt < 4; ++dt) {
        const uint16_t* vr = Vc + (dt * 16 + li) * 64;
        vf[dt][0] = ldb8(vr + ((lg * 8) ^ fsw));
        vf[dt][1] = ldb8(vr + ((32 + lg * 8) ^ fsw));
      }

      if (kt == qbl) {   // diagonal tile: causal mask -> exp2 gives exact 0
        const int qloc = (w << 4) + li;
#pragma unroll
        for (int tt = 0; tt < 4; ++tt) {
          const int key = (tt << 4) + (lg << 2);
#pragma unroll
          for (int r = 0; r < 4; ++r)
            if (key + r > qloc) s[tt][r] = -1e30f;
        }
      }

      // ---- no-max softmax: P = exp2(s), per-lane partial l
      float lsum = 0.f;
      ushort4 pk[4];
#pragma unroll
      for (int tt = 0; tt < 4; ++tt) {
        f32x4 p;
        p[0] = __builtin_amdgcn_exp2f(s[tt][0]);
        p[1] = __builtin_amdgcn_exp2f(s[tt][1]);
        p[2] = __builtin_amdgcn_exp2f(s[tt][2]);
        p[3] = __builtin_amdgcn_exp2f(s[tt][3]);
        lsum += (p[0] + p[1]) + (p[2] + p[3]);
        pk[tt] = pack4(p);
      }
      l_r += lsum;

      // ---- P relayout via per-wave LDS slab
#pragma unroll
      for (int tt = 0; tt < 4; ++tt)
        *(ushort4*)&P[w][li][(tt << 4) + (lg << 2)] = pk[tt];
      asm volatile("s_waitcnt lgkmcnt(0)" ::: "memory");

      const bf16x8 pb0 = ldb8(&P[w][li][lg * 8]);
      const bf16x8 pb1 = ldb8(&P[w][li][32 + lg * 8]);
      __builtin_amdgcn_s_setprio(1);
#pragma unroll
      for (int dt = 0; dt < 4; ++dt) {
        o[dt] = MFMA(vf[dt][0], pb0, o[dt]);
        o[dt] = MFMA(vf[dt][1], pb1, o[dt]);
      }
      __builtin_amdgcn_s_setprio(0);

      __syncthreads();
      cur ^= 1;
    }

    // final l reduce across the 4 lg-groups sharing q = li
    l_r += __shfl_xor(l_r, 16);
    l_r += __shfl_xor(l_r, 32);
    const float inv = 1.0f / l_r;
    const int qg = b * 2048 + qrow + li;
#pragma unroll
    for (int dt = 0; dt < 4; ++dt) {
      f32x4 ov = o[dt];
      ov[0] *= inv; ov[1] *= inv; ov[2] *= inv; ov[3] *= inv;
      *(ushort4*)(ctx + (size_t)qg * 1024 + h * 64 + (dt << 4) + (lg << 2)) = pack4(ov);
    }
  }
}

// ---------------------------------------------------------------- launch
extern "C" void kernel_launch(void* const* d_in, const int* in_sizes, int n_in,
                              void* d_out, int out_size, void* d_ws, size_t ws_size,
                              hipStream_t stream) {
  const float* x  = (const float*)d_in[0];
  const float* Wq = (const float*)d_in[1];
  const float* Wk = (const float*)d_in[2];
  const float* Wv = (const float*)d_in[3];
  const float* Wo = (const float*)d_in[4];
  const float* bo = (const float*)d_in[5];
  float* out = (float*)d_out;

  char* ws = (char*)d_ws;
  uint16_t* xb   = (uint16_t*)(ws);                 // 8MB (dead after QKV gemm)
  uint16_t* Wqkv = (uint16_t*)(ws + ( 8u << 20));   // 6MB: Wq|Wk|Wv contiguous
  uint16_t* Wob  = (uint16_t*)(ws + (14u << 20));   // 2MB
  uint16_t* Qb   = (uint16_t*)(ws + (16u << 20));   // 8MB
  uint16_t* Kb   = (uint16_t*)(ws + (24u << 20));   // 8MB
  uint16_t* Vt   = (uint16_t*)(ws + (32u << 20));   // 8MB
  uint16_t* Ctx  = (uint16_t*)(ws);                 // overlays xb

  cvt_all<<<8192, 256, 0, stream>>>(x, Wq, Wk, Wv, Wo, xb, Wqkv, Wob);

  // fused QKV projection: 256x192 tiles, grid 16x16 = 256 blocks (1/CU)
  gemm_qkv<<<dim3(16, 16), 512, 0, stream>>>(xb, Wqkv, Qb, Kb, Vt);

  // attention: 704 balanced blocks (XCD-mapped), 4 waves, ~2.75 blocks/CU
  attn_fwd<<<704, 256, 0, stream>>>(Qb, Kb, Vt, Ctx);

  // output projection + bias: 128x128 tiles, grid 8x32 = 256 blocks (1/CU)
  gemm_out<<<dim3(8, 32), 512, 0, stream>>>(Ctx, Wob, out, bo);
}

// Round 17
// 97.660 us; speedup vs baseline: 1.0710x; 1.0385x over previous
//
#include <hip/hip_runtime.h>
#include <stdint.h>

#define SEQ   2048
#define DEMB  1024
#define NH    16
#define HD    64
#define MROWS 4096   // BS*SEQ

typedef __bf16 bf16x8 __attribute__((ext_vector_type(8)));
typedef __bf16 bf16x4 __attribute__((ext_vector_type(4)));
typedef float  f32x4  __attribute__((ext_vector_type(4)));

#define MFMA(a, b, c) __builtin_amdgcn_mfma_f32_16x16x32_bf16((a), (b), (c), 0, 0, 0)
#define VMCNT(n) asm volatile("s_waitcnt vmcnt(" #n ")" ::: "memory")

static __device__ __forceinline__ void bar() {
  asm volatile("" ::: "memory");
  __builtin_amdgcn_s_barrier();
  asm volatile("" ::: "memory");
}

static __device__ __forceinline__ uint16_t f2bf(float f) {
  union { __bf16 b; uint16_t u; } c;
  c.b = (__bf16)f;
  return c.u;
}

static __device__ __forceinline__ ushort4 pack4(f32x4 f) {
  union { bf16x4 b; ushort4 u; } c;
  c.b[0] = (__bf16)f[0]; c.b[1] = (__bf16)f[1];
  c.b[2] = (__bf16)f[2]; c.b[3] = (__bf16)f[3];
  return c.u;
}

static __device__ __forceinline__ bf16x8 ldb8(const uint16_t* p) {
  union { uint4 i; bf16x8 b; } u;
  u.i = *(const uint4*)p;
  return u.b;
}

static __device__ __forceinline__ void gld_lds16(const uint16_t* g, uint16_t* l) {
  __builtin_amdgcn_global_load_lds(
      (const __attribute__((address_space(1))) uint32_t*)(g),
      (__attribute__((address_space(3))) uint32_t*)(l),
      16, 0, 0);
}

// ---------------------------------------------------------------- fused converts
__global__ __launch_bounds__(256) void cvt_all(const float* __restrict__ x,
                                               const float* __restrict__ wq,
                                               const float* __restrict__ wk,
                                               const float* __restrict__ wv,
                                               const float* __restrict__ wo,
                                               uint16_t* __restrict__ xb,
                                               uint16_t* __restrict__ wqkv,
                                               uint16_t* __restrict__ wob) {
  const int bid = blockIdx.x;
  const float* src; uint16_t* dst; int off;
  if (bid < 4096)      { src = x;  dst = xb;                 off = bid; }
  else if (bid < 5120) { src = wq; dst = wqkv;               off = bid - 4096; }
  else if (bid < 6144) { src = wk; dst = wqkv + (1u << 20);  off = bid - 5120; }
  else if (bid < 7168) { src = wv; dst = wqkv + (2u << 20);  off = bid - 6144; }
  else                 { src = wo; dst = wob;                off = bid - 7168; }
  const int i = (off * 256 + threadIdx.x) * 4;
  float4 v = *(const float4*)(src + i);
  f32x4 f; f[0] = v.x; f[1] = v.y; f[2] = v.z; f[3] = v.w;
  *(ushort4*)(dst + i) = pack4(f);
}

// ---------------------------------------------------------------- QKV GEMM
// (R10 exact: 256x192, BK=64, 8 waves 2Mx4N wave 128x48, grid 16x16 = 1/CU,
// 112 KB double-buffered LDS, conflict-free XOR swizzle, V^T via LDS slab)
__global__ __launch_bounds__(512, 2) void gemm_qkv(const uint16_t* __restrict__ A,
                                                   const uint16_t* __restrict__ B,
                                                   uint16_t* __restrict__ Cq,
                                                   uint16_t* __restrict__ Ck,
                                                   uint16_t* __restrict__ Cvt) {
  constexpr int K = 1024;
  __shared__ uint16_t lds[57344];      // 112 KB

  const int bcol = blockIdx.x * 192;
  const int brow = blockIdx.y << 8;

  const int t  = threadIdx.x;
  const int l  = t & 63;
  const int li = l & 15, lg = l >> 4;
  const int w  = t >> 6;               // 0..7
  const int wm = w >> 2;               // row half: wm*128
  const int wn = w & 3;                // col quarter: wn*48

  const int srow = t >> 3;
  const int scol = ((t & 7) ^ (srow & 7)) << 3;
  const uint16_t* gA = A + (size_t)(brow + srow) * K + scol;
  const uint16_t* gB = B + (size_t)(bcol + srow) * K + scol;

  auto stage = [&](int buf, int k0) {
    uint16_t* as = lds + buf * 16384;
    uint16_t* bs = lds + 32768 + buf * 12288;
    gld_lds16(gA + k0,                    as + t * 8);
    gld_lds16(gA + (size_t)64 * K + k0,   as + 4096 + t * 8);
    gld_lds16(gA + (size_t)128 * K + k0,  as + 8192 + t * 8);
    gld_lds16(gA + (size_t)192 * K + k0,  as + 12288 + t * 8);
    gld_lds16(gB + k0,                    bs + t * 8);
    gld_lds16(gB + (size_t)64 * K + k0,   bs + 4096 + t * 8);
    gld_lds16(gB + (size_t)128 * K + k0,  bs + 8192 + t * 8);
  };

  const int sw = li & 7;
  auto ldA = [&](int buf, int kh, int fi) {
    const int row = wm * 128 + fi * 16 + li;
    return ldb8(&lds[buf * 16384 + (row << 6) + ((((kh << 2) + lg) ^ sw) << 3)]);
  };
  auto ldB = [&](int buf, int kh, int ni) {
    const int row = wn * 48 + ni * 16 + li;
    return ldb8(&lds[32768 + buf * 12288 + (row << 6) + ((((kh << 2) + lg) ^ sw) << 3)]);
  };

  f32x4 acc[8][3] = {};

  stage(0, 0);
  __syncthreads();
  int cur = 0;

  for (int k0 = 0; k0 < K; k0 += 64) {
    if (k0 + 64 < K) stage(cur ^ 1, k0 + 64);

#pragma unroll
    for (int kh = 0; kh < 2; ++kh) {
      bf16x8 af[8], bfr[3];
#pragma unroll
      for (int ni = 0; ni < 3; ++ni) bfr[ni] = ldB(cur, kh, ni);
#pragma unroll
      for (int fi = 0; fi < 8; ++fi) af[fi] = ldA(cur, kh, fi);
      __builtin_amdgcn_s_setprio(1);
#pragma unroll
      for (int fi = 0; fi < 8; ++fi)
#pragma unroll
        for (int ni = 0; ni < 3; ++ni)
          acc[fi][ni] = MFMA(af[fi], bfr[ni], acc[fi][ni]);
      __builtin_amdgcn_s_setprio(0);
    }

    __syncthreads();
    cur ^= 1;
  }

  // ---- epilogue. Q/K: direct stores. V: per-wave LDS transpose -> coalesced.
  uint16_t* slab = lds + w * 6800;
  bool anyV = false;

#pragma unroll
  for (int mi = 0; mi < 8; ++mi) {
#pragma unroll
    for (int ni = 0; ni < 3; ++ni) {
      const int col = bcol + wn * 48 + ni * 16 + li;
      const int row = brow + wm * 128 + mi * 16 + lg * 4;   // + r
      if (col < 1024) {
#pragma unroll
        for (int r = 0; r < 4; ++r)
          Cq[(size_t)(row + r) * 1024 + col] = f2bf(acc[mi][ni][r] * 0.18033688f);
      } else if (col < 2048) {
#pragma unroll
        for (int r = 0; r < 4; ++r)
          Ck[(size_t)(row + r) * 1024 + (col - 1024)] = f2bf(acc[mi][ni][r]);
      } else {
        anyV = true;
        *(ushort4*)&slab[(ni * 16 + li) * 136 + mi * 16 + lg * 4] = pack4(acc[mi][ni]);
      }
    }
  }

  if (anyV) {
    asm volatile("s_waitcnt lgkmcnt(0)" ::: "memory");
    const int m0 = brow + wm * 128;
    const size_t mbase = (size_t)((m0 >> 11) << 10) * 2048 + (m0 & 2047);
#pragma unroll
    for (int cc = 0; cc < 12; ++cc) {
      const int c_loc = cc * 4 + lg;
      const int cglob = bcol + wn * 48 + c_loc;
      if (cglob >= 2048) {
        const int c = cglob - 2048;
        uint4 v = *(const uint4*)&slab[c_loc * 136 + li * 8];
        *(uint4*)(Cvt + (size_t)c * 2048 + mbase + li * 8) = v;
      }
    }
  }
}

// ---------------------------------------------------------------- out projection
// (R10 exact: 128x128, BK=64, 8 waves wave 64x32, grid 8x32 = 1/CU)
__global__ __launch_bounds__(512, 2) void gemm_out(const uint16_t* __restrict__ A,
                                                   const uint16_t* __restrict__ B,
                                                   float* __restrict__ Cf,
                                                   const float* __restrict__ bias) {
  constexpr int K = 1024;
  __shared__ uint16_t As[2][128 * 64];
  __shared__ uint16_t Bs[2][128 * 64];

  const int bcol = blockIdx.x << 7;
  const int brow = blockIdx.y << 7;

  const int t  = threadIdx.x;
  const int l  = t & 63;
  const int li = l & 15, lg = l >> 4;
  const int w  = t >> 6;
  const int wm = w >> 2;
  const int wn = w & 3;

  const int srow = t >> 3;
  const int scol = ((t & 7) ^ (srow & 7)) << 3;
  const uint16_t* gA = A + (size_t)(brow + srow) * K + scol;
  const uint16_t* gB = B + (size_t)(bcol + srow) * K + scol;

  auto stage = [&](int buf, int k0) {
    gld_lds16(gA + k0,                  &As[buf][t * 8]);
    gld_lds16(gA + (size_t)64 * K + k0, &As[buf][4096 + t * 8]);
    gld_lds16(gB + k0,                  &Bs[buf][t * 8]);
    gld_lds16(gB + (size_t)64 * K + k0, &Bs[buf][4096 + t * 8]);
  };

  const int sw = li & 7;
  auto ldA = [&](int buf, int kh, int fi) {
    const int row = wm * 64 + fi * 16 + li;
    return ldb8(&As[buf][(row << 6) + ((((kh << 2) + lg) ^ sw) << 3)]);
  };
  auto ldB = [&](int buf, int kh, int ni) {
    const int row = wn * 32 + ni * 16 + li;
    return ldb8(&Bs[buf][(row << 6) + ((((kh << 2) + lg) ^ sw) << 3)]);
  };

  f32x4 acc[4][2] = {};

  stage(0, 0);
  __syncthreads();
  int cur = 0;

  for (int k0 = 0; k0 < K; k0 += 64) {
    if (k0 + 64 < K) stage(cur ^ 1, k0 + 64);

#pragma unroll
    for (int kh = 0; kh < 2; ++kh) {
      bf16x8 af[4], bfr[2];
#pragma unroll
      for (int ni = 0; ni < 2; ++ni) bfr[ni] = ldB(cur, kh, ni);
#pragma unroll
      for (int fi = 0; fi < 4; ++fi) af[fi] = ldA(cur, kh, fi);
      __builtin_amdgcn_s_setprio(1);
#pragma unroll
      for (int fi = 0; fi < 4; ++fi)
#pragma unroll
        for (int ni = 0; ni < 2; ++ni)
          acc[fi][ni] = MFMA(af[fi], bfr[ni], acc[fi][ni]);
      __builtin_amdgcn_s_setprio(0);
    }

    __syncthreads();
    cur ^= 1;
  }

#pragma unroll
  for (int mi = 0; mi < 4; ++mi) {
#pragma unroll
    for (int ni = 0; ni < 2; ++ni) {
      const int row = brow + wm * 64 + mi * 16 + lg * 4;
      const int col = bcol + wn * 32 + ni * 16 + li;
      const float bv = bias[col];
#pragma unroll
      for (int r = 0; r < 4; ++r)
        Cf[(size_t)(row + r) * 1024 + col] = acc[mi][ni][r] + bv;
    }
  }
}

// ---------------------------------------------------------------- flash attention
// R17: KVBLK=128 (tiles per block 33 -> 17, uniform via (pr, 31-pr) pairing;
// per-key barrier/P-round-trip cost HALVED). 4 waves, QBLK=64, swapped-operand
// no-max exp2 softmax. K[2][128x64] + V[2][64x128] double-buffered (64 KB ->
// 2 blocks/CU); P slab lives INSIDE Kl[cur] (K(t) dead after QK(t) + barrier),
// swizzled granule^li both sides. Counted vmcnt (FIFO-audited), raw barriers:
//   top invariant: V(t) 4 outstanding; issue K(t+1),V(t+1) (8);
//   QK(t); VMCNT(8) [V(t) landed]; bar M [visible + Kl reusable];
//   softmax -> P in Kl[cur]; lgkm; P/V reads; PV;
//   VMCNT(4) [K(t+1) landed]; bar E [visible + reads done]; flip.
__global__ __launch_bounds__(256, 2) void attn_fwd(const uint16_t* __restrict__ Q,
                                                   const uint16_t* __restrict__ K,
                                                   const uint16_t* __restrict__ Vt,
                                                   uint16_t* __restrict__ ctx) {
  const int id   = blockIdx.x;               // 0..511; id&7 = XCD
  const int rank = id >> 3;                  // 0..63
  const int bh   = (id & 7) * 4 + (rank >> 4);
  const int pr   = rank & 15;                // pair index 0..15
  const int b = bh >> 4, h = bh & 15;

  const int t  = threadIdx.x;
  const int w  = t >> 6, l = t & 63;
  const int li = l & 15, lg = l >> 4;

  __shared__ uint16_t Kl[2][128 * 64];  // 32 KB (key rows x 64 d), swizzled
  __shared__ uint16_t Vl[2][64 * 128];  // 32 KB (d rows x 128 keys), swizzled

  const uint16_t* Kg = K + (size_t)(b * 2048) * 1024 + h * 64;
  const uint16_t* Vg = Vt + (size_t)(b * 1024 + h * 64) * 2048;

  // K staging: 4 calls x 32 rows; LDS[r][s] = glob[r][s ^ (r&7)]
  const int krow  = t >> 3;                         // 0..31
  const int kscol = ((t & 7) ^ (krow & 7)) << 3;
  // V staging: 4 calls x 16 rows; LDS[d][s] = glob[d][s ^ (d&15)]
  const int vrow  = t >> 4;                         // 0..15
  const int vscol = ((t & 15) ^ vrow) << 3;

  auto stageK = [&](int buf, int kb) {
#pragma unroll
    for (int c = 0; c < 4; ++c)
      gld_lds16(Kg + (size_t)(kb + c * 32 + krow) * 1024 + kscol,
                &Kl[buf][c * 2048 + t * 8]);
  };
  auto stageV = [&](int buf, int kb) {
#pragma unroll
    for (int c = 0; c < 4; ++c)
      gld_lds16(Vg + (size_t)(c * 16 + vrow) * 2048 + kb + vscol,
                &Vl[buf][c * 2048 + t * 8]);
  };

  const int fsw = li & 7;

#pragma unroll 1
  for (int ph = 0; ph < 2; ++ph) {
    const int qbl = ph ? (31 - pr) : pr;
    const int nkt = (qbl >> 1) + 1;
    const int qrow = (qbl << 6) + (w << 4);
    const int qglob = qrow + li;
    const uint16_t* qp = Q + (size_t)(b * 2048 + qrow + li) * 1024 + h * 64 + lg * 8;
    const bf16x8 q0v = ldb8(qp);
    const bf16x8 q1v = ldb8(qp + 32);

    f32x4 o[4] = {};                   // O[d = dt*16 + lg*4 + r][q = li]
    float l_r = 0.f;
    int cur = 0;

    stageK(0, 0);
    stageV(0, 0);
    VMCNT(4);                          // my K(0) landed (V(0) + q drained too? q older -> drained)
    bar();                             // all waves' K(0) visible

    for (int kt = 0; kt < nkt; ++kt) {
      const int kb = kt << 7;
      const bool pf = (kt + 1 < nkt);
      if (pf) { stageK(cur ^ 1, kb + 128); stageV(cur ^ 1, kb + 128); }

      // QK swapped: s[tt][r] = S[key = kb + tt*16 + lg*4 + r][q = qglob]
      f32x4 s[8];
      __builtin_amdgcn_s_setprio(1);
#pragma unroll
      for (int tt = 0; tt < 8; ++tt) {
        const uint16_t* kr = &Kl[cur][(tt * 16 + li) << 6];
        f32x4 z = {};
        z = MFMA(ldb8(kr + ((lg ^ fsw) << 3)), q0v, z);
        z = MFMA(ldb8(kr + (((4 + lg) ^ fsw) << 3)), q1v, z);
        s[tt] = z;
      }
      __builtin_amdgcn_s_setprio(0);

      if (kb + 127 > qrow) {           // tile crosses/exceeds diagonal: mask
#pragma unroll
        for (int tt = 0; tt < 8; ++tt) {
          const int key = kb + (tt << 4) + (lg << 2);
#pragma unroll
          for (int r = 0; r < 4; ++r)
            if (key + r > qglob) s[tt][r] = -1e30f;
        }
      }

      if (pf) VMCNT(8); else VMCNT(0); // my V(t) landed (K(t+1),V(t+1) in flight)
      bar();                           // M: V(t) visible; all QK reads done

      // ---- no-max softmax -> P written into Kl[cur] (per-wave quarter),
      // physical granule = logical granule ^ li (conflict-free both sides)
      uint16_t* Pb = &Kl[cur][(w << 11) + (li << 7)];
      float lsum = 0.f;
#pragma unroll
      for (int tt = 0; tt < 8; ++tt) {
        f32x4 p;
        p[0] = __builtin_amdgcn_exp2f(s[tt][0]);
        p[1] = __builtin_amdgcn_exp2f(s[tt][1]);
        p[2] = __builtin_amdgcn_exp2f(s[tt][2]);
        p[3] = __builtin_amdgcn_exp2f(s[tt][3]);
        lsum += (p[0] + p[1]) + (p[2] + p[3]);
        *(ushort4*)(Pb + ((((tt << 1) + (lg >> 1)) ^ li) << 3) + ((lg & 1) << 2)) = pack4(p);
      }
      l_r += lsum;
      asm volatile("s_waitcnt lgkmcnt(0)" ::: "memory");

      bf16x8 pb[4];
#pragma unroll
      for (int ks = 0; ks < 4; ++ks)
        pb[ks] = ldb8(Pb + ((((ks << 2) + lg) ^ li) << 3));

      __builtin_amdgcn_s_setprio(1);
#pragma unroll
      for (int dt = 0; dt < 4; ++dt) {
        const uint16_t* vr = &Vl[cur][(dt * 16 + li) << 7];
#pragma unroll
        for (int ks = 0; ks < 4; ++ks)
          o[dt] = MFMA(ldb8(vr + ((((ks << 2) + lg) ^ li) << 3)), pb[ks], o[dt]);
      }
      __builtin_amdgcn_s_setprio(0);

      if (pf) VMCNT(4);                // my K(t+1) landed (V(t+1) in flight)
      bar();                           // E: K(t+1) visible; all P/V reads done
      cur ^= 1;
    }

    // final l reduce across the 4 lg-groups sharing q = li
    l_r += __shfl_xor(l_r, 16);
    l_r += __shfl_xor(l_r, 32);
    const float inv = 1.0f / l_r;
    const int qg = b * 2048 + qrow + li;
#pragma unroll
    for (int dt = 0; dt < 4; ++dt) {
      f32x4 ov = o[dt];
      ov[0] *= inv; ov[1] *= inv; ov[2] *= inv; ov[3] *= inv;
      *(ushort4*)(ctx + (size_t)qg * 1024 + h * 64 + (dt << 4) + (lg << 2)) = pack4(ov);
    }
  }
}

// ---------------------------------------------------------------- launch
extern "C" void kernel_launch(void* const* d_in, const int* in_sizes, int n_in,
                              void* d_out, int out_size, void* d_ws, size_t ws_size,
                              hipStream_t stream) {
  const float* x  = (const float*)d_in[0];
  const float* Wq = (const float*)d_in[1];
  const float* Wk = (const float*)d_in[2];
  const float* Wv = (const float*)d_in[3];
  const float* Wo = (const float*)d_in[4];
  const float* bo = (const float*)d_in[5];
  float* out = (float*)d_out;

  char* ws = (char*)d_ws;
  uint16_t* xb   = (uint16_t*)(ws);                 // 8MB (dead after QKV gemm)
  uint16_t* Wqkv = (uint16_t*)(ws + ( 8u << 20));   // 6MB: Wq|Wk|Wv contiguous
  uint16_t* Wob  = (uint16_t*)(ws + (14u << 20));   // 2MB
  uint16_t* Qb   = (uint16_t*)(ws + (16u << 20));   // 8MB
  uint16_t* Kb   = (uint16_t*)(ws + (24u << 20));   // 8MB
  uint16_t* Vt   = (uint16_t*)(ws + (32u << 20));   // 8MB
  uint16_t* Ctx  = (uint16_t*)(ws);                 // overlays xb

  cvt_all<<<8192, 256, 0, stream>>>(x, Wq, Wk, Wv, Wo, xb, Wqkv, Wob);

  // fused QKV projection: 256x192 tiles, grid 16x16 = 256 blocks (1/CU)
  gemm_qkv<<<dim3(16, 16), 512, 0, stream>>>(xb, Wqkv, Qb, Kb, Vt);

  // attention: 512 blocks (XCD-mapped, causal-paired), KVBLK=128, 2/CU
  attn_fwd<<<512, 256, 0, stream>>>(Qb, Kb, Vt, Ctx);

  // output projection + bias: 128x128 tiles, grid 8x32 = 256 blocks (1/CU)
  gemm_out<<<dim3(8, 32), 512, 0, stream>>>(Ctx, Wob, out, bo);
}